// Round 6
// baseline (1434.233 us; speedup 1.0000x reference)
//
#include <hip/hip_runtime.h>

// GCN 2-layer: N=100000, E=6400000, IN=128, HID=16, OUT=32.
// R6: bgather (126us, 13.8% occupancy, latency-bound) replaced by
// LDS-accumulator gather: no in-bucket sort, ds_add_f32 into a 16KB
// 256x16 accumulator (swizzled +dl to spread banks), bucket SPLIT=4
// blocks (1564 blocks, ~6/CU) with 4-edge unroll for MLP. Features
// pre-scaled by dis (gemm1/combine epilogues) so the edge loop does
// ONE random 16B load per (edge,quad) -- dis[s] loads eliminated.
//   t1s = dis * (x@W1)
//   h1s = dis * relu(dis*(sum_in t1s[s] + t1s[self]) + b1)
//   v   = dis * (sum_in h1s[s] + h1s[self])
//   out = v @ W2 + b2

#define IN_CH 128
#define HID 16
#define OUT_CH 32

#define TILE 8192        // edges per phase-A workgroup
#define BSHIFT 8         // bucket = dst >> 8  (256 nodes per bucket)
#define BNODES 256
#define BCAP 18432       // bucket capacity; E[16384], sigma 128 -> +16 sigma
#define NBUCK_MAX 512
#define SPLIT 4          // gather blocks per bucket

// ---------------- Phase A: bucket scatter (unchanged, proven) ----------------
__global__ __launch_bounds__(256) void bucket_kernel(
    const int* __restrict__ src, const int* __restrict__ dst,
    int* __restrict__ bcur, int* __restrict__ bpacked, int E, int nbuck) {
  __shared__ int stage[TILE];
  __shared__ unsigned short stg_b[TILE];
  __shared__ int hist[NBUCK_MAX];
  __shared__ int scn[NBUCK_MAX];
  __shared__ int cur[NBUCK_MAX];
  __shared__ int gbase[NBUCK_MAX];

  int tid = threadIdx.x;
  int base = blockIdx.x * TILE;
  int cnt_t = E - base; if (cnt_t > TILE) cnt_t = TILE;

  hist[tid] = 0; hist[tid + 256] = 0;
  __syncthreads();
  for (int i = tid; i < cnt_t; i += 256)
    atomicAdd(&hist[dst[base + i] >> BSHIFT], 1);
  __syncthreads();
  scn[tid] = hist[tid]; scn[tid + 256] = hist[tid + 256];
  __syncthreads();
  for (int off = 1; off < 512; off <<= 1) {
    int a0 = (tid >= off) ? scn[tid - off] : 0;
    int i1 = tid + 256;
    int a1 = (i1 >= off) ? scn[i1 - off] : 0;
    __syncthreads();
    scn[tid] += a0; scn[i1] += a1;
    __syncthreads();
  }
  for (int b = tid; b < 512; b += 256) {
    int excl = scn[b] - hist[b];
    cur[b] = excl;
    int c = hist[b];
    gbase[b] = (b < nbuck && c > 0) ? atomicAdd(&bcur[b], c) : 0;
  }
  __syncthreads();
  for (int i = tid; i < cnt_t; i += 256) {
    int d = dst[base + i];
    int s = src[base + i];
    int b = d >> BSHIFT;
    int r = atomicAdd(&cur[b], 1);
    stage[r] = ((d & (BNODES - 1)) << 17) | s;
    stg_b[r] = (unsigned short)b;
  }
  __syncthreads();
  for (int i = tid; i < cnt_t; i += 256) {
    int b = stg_b[i];
    int excl = scn[b] - hist[b];
    int pos = gbase[b] + (i - excl);
    if (pos < BCAP) bpacked[(size_t)b * BCAP + pos] = stage[i];
  }
}

// ---------------- degree -> dis, per bucket ----------------
__global__ __launch_bounds__(256) void degdis_kernel(
    const int* __restrict__ bpacked, const int* __restrict__ bcur,
    float* __restrict__ dis, int N) {
  __shared__ int hist[BNODES];
  int b = blockIdx.x;
  int tid = threadIdx.x;
  hist[tid] = 0;
  __syncthreads();
  int ecnt = bcur[b]; if (ecnt > BCAP) ecnt = BCAP;
  const int* bp = bpacked + (size_t)b * BCAP;
  for (int i = tid; i < ecnt; i += 256) atomicAdd(&hist[bp[i] >> 17], 1);
  __syncthreads();
  int node = (b << BSHIFT) + tid;
  if (node < N) dis[node] = rsqrtf((float)hist[tid] + 1.0f);
}

// ---------------- t1s = dis * (x @ W1) ----------------
__global__ __launch_bounds__(256) void gemm1_kernel(
    const float* __restrict__ x, const float* __restrict__ W1,
    const float* __restrict__ dis, float* __restrict__ t1s, int N) {
  __shared__ __align__(16) float xs[64 * 132];
  __shared__ __align__(16) float w1s[128 * 16];
  int tid = threadIdx.x;
  int nb = blockIdx.x * 64;
  for (int i = tid; i < 128 * 16; i += 256) w1s[i] = W1[i];
  int maxRows = N - nb; if (maxRows > 64) maxRows = 64;
  const float4* xg = (const float4*)(x + (size_t)nb * IN_CH);
  for (int i = tid; i < maxRows * 32; i += 256) {
    float4 v = xg[i];
    int row = i >> 5;
    int k4 = (i & 31) << 2;
    *((float4*)&xs[row * 132 + k4]) = v;
  }
  __syncthreads();
  int nl = tid >> 2;
  int cg = tid & 3;
  int node = nb + nl;
  float4 acc = make_float4(0.f, 0.f, 0.f, 0.f);
  const float* xrow = &xs[nl * 132];
  const float4* w4 = (const float4*)w1s;
  for (int k = 0; k < 128; ++k) {
    float xv = xrow[k];
    float4 wv = w4[k * 4 + cg];
    acc.x += xv * wv.x; acc.y += xv * wv.y;
    acc.z += xv * wv.z; acc.w += xv * wv.w;
  }
  if (node < N) {
    float dd = dis[node];
    acc.x *= dd; acc.y *= dd; acc.z *= dd; acc.w *= dd;
    *((float4*)&t1s[(size_t)node * HID + cg * 4]) = acc;
  }
}

// ---------------- edge-parallel LDS-accumulator gather ----------------
// channel c of local node dl is stored at acc[dl*16 + ((c+dl)&15)] (swizzle)
__global__ __launch_bounds__(256) void gather_kernel(
    const int* __restrict__ bpacked, const int* __restrict__ bcur,
    const float* __restrict__ feat, float* __restrict__ pacc) {
  __shared__ float acc[BNODES * HID];   // 16 KB
  int blk = blockIdx.x;
  int b = blk >> 2;          // SPLIT = 4
  int h = blk & 3;
  int tid = threadIdx.x;
  for (int i = tid; i < BNODES * HID; i += 256) acc[i] = 0.f;
  __syncthreads();
  int ecnt = bcur[b]; if (ecnt > BCAP) ecnt = BCAP;
  int per = (ecnt + SPLIT - 1) / SPLIT;
  int beg = h * per;
  int end = beg + per; if (end > ecnt) end = ecnt;
  const int* bp = bpacked + (size_t)b * BCAP;
  int q4 = (tid & 3) * 4;
  int e = beg + (tid >> 2);
  for (; e + 192 < end; e += 256) {
    int p0 = bp[e]; int p1 = bp[e + 64]; int p2 = bp[e + 128]; int p3 = bp[e + 192];
    float4 f0 = *(const float4*)(feat + (size_t)(p0 & 0x1FFFF) * HID + q4);
    float4 f1 = *(const float4*)(feat + (size_t)(p1 & 0x1FFFF) * HID + q4);
    float4 f2 = *(const float4*)(feat + (size_t)(p2 & 0x1FFFF) * HID + q4);
    float4 f3 = *(const float4*)(feat + (size_t)(p3 & 0x1FFFF) * HID + q4);
    int d0 = p0 >> 17; int d1 = p1 >> 17; int d2 = p2 >> 17; int d3 = p3 >> 17;
    float* a0 = acc + d0 * HID;
    float* a1 = acc + d1 * HID;
    float* a2 = acc + d2 * HID;
    float* a3 = acc + d3 * HID;
    atomicAdd(a0 + ((q4 + 0 + d0) & 15), f0.x);
    atomicAdd(a0 + ((q4 + 1 + d0) & 15), f0.y);
    atomicAdd(a0 + ((q4 + 2 + d0) & 15), f0.z);
    atomicAdd(a0 + ((q4 + 3 + d0) & 15), f0.w);
    atomicAdd(a1 + ((q4 + 0 + d1) & 15), f1.x);
    atomicAdd(a1 + ((q4 + 1 + d1) & 15), f1.y);
    atomicAdd(a1 + ((q4 + 2 + d1) & 15), f1.z);
    atomicAdd(a1 + ((q4 + 3 + d1) & 15), f1.w);
    atomicAdd(a2 + ((q4 + 0 + d2) & 15), f2.x);
    atomicAdd(a2 + ((q4 + 1 + d2) & 15), f2.y);
    atomicAdd(a2 + ((q4 + 2 + d2) & 15), f2.z);
    atomicAdd(a2 + ((q4 + 3 + d2) & 15), f2.w);
    atomicAdd(a3 + ((q4 + 0 + d3) & 15), f3.x);
    atomicAdd(a3 + ((q4 + 1 + d3) & 15), f3.y);
    atomicAdd(a3 + ((q4 + 2 + d3) & 15), f3.z);
    atomicAdd(a3 + ((q4 + 3 + d3) & 15), f3.w);
  }
  for (; e < end; e += 64) {
    int p = bp[e];
    float4 f = *(const float4*)(feat + (size_t)(p & 0x1FFFF) * HID + q4);
    int d = p >> 17;
    float* a = acc + d * HID;
    atomicAdd(a + ((q4 + 0 + d) & 15), f.x);
    atomicAdd(a + ((q4 + 1 + d) & 15), f.y);
    atomicAdd(a + ((q4 + 2 + d) & 15), f.z);
    atomicAdd(a + ((q4 + 3 + d) & 15), f.w);
  }
  __syncthreads();
  float4* dp = (float4*)(pacc + (size_t)blk * (BNODES * HID));
  const float4* sp = (const float4*)acc;
  for (int i = tid; i < BNODES * HID / 4; i += 256) dp[i] = sp[i];
}

// ---------------- combine partials + epilogue ----------------
// layer1 (RELU=true):  out = dis * relu(dis*(sum + self) + bias)   [= h1s]
// layer2 (RELU=false): out = dis * (sum + self)                    [= v]
template <bool RELU>
__global__ __launch_bounds__(256) void combine_kernel(
    const float* __restrict__ pacc, const float* __restrict__ selff,
    const float* __restrict__ dis, const float* __restrict__ bias,
    float* __restrict__ outf, int N) {
  int idx = blockIdx.x * 256 + threadIdx.x;
  if (idx >= N * HID) return;
  int node = idx >> 4;
  int c = idx & 15;
  int b = node >> BSHIFT;
  int dl = node & (BNODES - 1);
  size_t base = ((size_t)b * SPLIT) * (BNODES * HID) + dl * HID + ((c + dl) & 15);
  float s = pacc[base] + pacc[base + BNODES * HID] +
            pacc[base + 2 * BNODES * HID] + pacc[base + 3 * BNODES * HID];
  float dd = dis[node];
  float val = dd * (s + selff[idx]);
  if (RELU) val = fmaxf(val + bias[c], 0.f) * dd;
  outf[idx] = val;
}

// ---------------- out = v @ W2 + b2 ----------------
__global__ __launch_bounds__(256) void out_kernel(
    const float* __restrict__ v, const float* __restrict__ W2,
    const float* __restrict__ b2, float* __restrict__ out, int N) {
  __shared__ __align__(16) float vs[32 * 17];
  __shared__ __align__(16) float w2s[16 * 32];
  __shared__ __align__(16) float b2s[32];
  int tid = threadIdx.x;
  int nb = blockIdx.x * 32;
  for (int i = tid; i < 16 * 32; i += 256) w2s[i] = W2[i];
  if (tid < 32) b2s[tid] = b2[tid];
  for (int i = tid; i < 32 * 16; i += 256) {
    int nl = i >> 4;
    int c = i & 15;
    int node = nb + nl;
    float val = 0.f;
    if (node < N) val = v[(size_t)node * HID + c];
    vs[nl * 17 + c] = val;
  }
  __syncthreads();
  int nl = tid >> 3;
  int og = tid & 7;
  int node = nb + nl;
  float4 acc = make_float4(0.f, 0.f, 0.f, 0.f);
  const float4* w24 = (const float4*)w2s;
  const float* vrow = &vs[nl * 17];
  for (int c = 0; c < 16; ++c) {
    float vv = vrow[c];
    float4 wv = w24[c * 8 + og];
    acc.x += vv * wv.x; acc.y += vv * wv.y;
    acc.z += vv * wv.z; acc.w += vv * wv.w;
  }
  float4 bb = ((const float4*)b2s)[og];
  acc.x += bb.x; acc.y += bb.y; acc.z += bb.z; acc.w += bb.w;
  if (node < N) {
    *((float4*)&out[(size_t)node * OUT_CH + og * 4]) = acc;
  }
}

extern "C" void kernel_launch(void* const* d_in, const int* in_sizes, int n_in,
                              void* d_out, int out_size, void* d_ws, size_t ws_size,
                              hipStream_t stream) {
  const float* x  = (const float*)d_in[0];
  const int* ei   = (const int*)d_in[1];   // int64 in reference -> int32 here
  const float* W1 = (const float*)d_in[2];
  const float* b1 = (const float*)d_in[3];
  const float* W2 = (const float*)d_in[4];
  const float* b2 = (const float*)d_in[5];
  float* out = (float*)d_out;

  int N = in_sizes[0] / IN_CH;
  int E = in_sizes[1] / 2;
  const int* src = ei;
  const int* dst = ei + E;

  int nbuck = (N + BNODES - 1) >> BSHIFT;          // 391

  int*   bcur    = (int*)d_ws;                                 // 512
  float* dis     = (float*)(bcur + 512);                       // N
  float* t1s     = dis + N;                                    // 16N (reused as v)
  float* h1s     = t1s + (size_t)N * HID;                      // 16N
  int*   bpacked = (int*)(h1s + (size_t)N * HID);              // nbuck*BCAP (28.8 MB)
  float* pacc    = (float*)(bpacked + (size_t)nbuck * BCAP);   // nbuck*SPLIT*4096 (25.6 MB)
  float* v       = t1s;   // overlay: t1s dead after combine1
  // total ~= 0.4 + 6.4 + 6.4 + 28.8 + 25.6 MB ~= 67.7 MB

  hipMemsetAsync(bcur, 0, 512 * sizeof(int), stream);

  bucket_kernel<<<(E + TILE - 1) / TILE, 256, 0, stream>>>(
      src, dst, bcur, bpacked, E, nbuck);
  degdis_kernel<<<nbuck, 256, 0, stream>>>(bpacked, bcur, dis, N);
  gemm1_kernel<<<(N + 63) / 64, 256, 0, stream>>>(x, W1, dis, t1s, N);
  gather_kernel<<<nbuck * SPLIT, 256, 0, stream>>>(bpacked, bcur, t1s, pacc);
  combine_kernel<true><<<((size_t)N * HID + 255) / 256, 256, 0, stream>>>(
      pacc, t1s, dis, b1, h1s, N);
  gather_kernel<<<nbuck * SPLIT, 256, 0, stream>>>(bpacked, bcur, h1s, pacc);
  combine_kernel<false><<<((size_t)N * HID + 255) / 256, 256, 0, stream>>>(
      pacc, h1s, dis, nullptr, v, N);
  out_kernel<<<(N + 31) / 32, 256, 0, stream>>>(v, W2, b2, out, N);
}

// Round 7
// 443.173 us; speedup vs baseline: 3.2363x; 3.2363x over previous
//
#include <hip/hip_runtime.h>

// GCN 2-layer: N=100000, E=6400000, IN=128, HID=16, OUT=32.
// R7: revert R6's LDS-atomic gather (589us, serialized ds_add). Back to
// R5's sort-then-register-accumulate bgather with its real limiters fixed:
//   (a) half-bucket blocks (128 nodes, 38.4KB LDS) -> 4 blocks/CU, 782 blocks
//       (R5: 76.8KB, 2/CU, 391 blocks, 13.8% occupancy)
//   (b) features pre-scaled by dis -> no per-edge dis[s] load
//   (c) 4-edge unrolled inner loop -> 4 outstanding float4 loads/thread
//   t1s = dis * (x@W1)
//   h1s = dis * relu(dd*(sum_in t1s[s] + t1s[self]) + b1)    [bgather1]
//   v   = dis * (sum_in h1s[s] + h1s[self])                  [bgather2]
//   out = v @ W2 + b2

#define IN_CH 128
#define HID 16
#define OUT_CH 32

#define TILE 8192        // edges per phase-A workgroup
#define BSHIFT 8         // bucket = dst >> 8  (256 nodes per bucket)
#define BNODES 256
#define BCAP 18432       // bucket capacity; E[16384], sigma 128 -> +16 sigma
#define NBUCK_MAX 512
#define HBCAP 9216       // half-bucket capacity; E[8192], sigma 90 -> +11 sigma

// ---------------- Phase A: bucket scatter (unchanged, proven) ----------------
__global__ __launch_bounds__(256) void bucket_kernel(
    const int* __restrict__ src, const int* __restrict__ dst,
    int* __restrict__ bcur, int* __restrict__ bpacked, int E, int nbuck) {
  __shared__ int stage[TILE];
  __shared__ unsigned short stg_b[TILE];
  __shared__ int hist[NBUCK_MAX];
  __shared__ int scn[NBUCK_MAX];
  __shared__ int cur[NBUCK_MAX];
  __shared__ int gbase[NBUCK_MAX];

  int tid = threadIdx.x;
  int base = blockIdx.x * TILE;
  int cnt_t = E - base; if (cnt_t > TILE) cnt_t = TILE;

  hist[tid] = 0; hist[tid + 256] = 0;
  __syncthreads();
  for (int i = tid; i < cnt_t; i += 256)
    atomicAdd(&hist[dst[base + i] >> BSHIFT], 1);
  __syncthreads();
  scn[tid] = hist[tid]; scn[tid + 256] = hist[tid + 256];
  __syncthreads();
  for (int off = 1; off < 512; off <<= 1) {
    int a0 = (tid >= off) ? scn[tid - off] : 0;
    int i1 = tid + 256;
    int a1 = (i1 >= off) ? scn[i1 - off] : 0;
    __syncthreads();
    scn[tid] += a0; scn[i1] += a1;
    __syncthreads();
  }
  for (int b = tid; b < 512; b += 256) {
    int excl = scn[b] - hist[b];
    cur[b] = excl;
    int c = hist[b];
    gbase[b] = (b < nbuck && c > 0) ? atomicAdd(&bcur[b], c) : 0;
  }
  __syncthreads();
  for (int i = tid; i < cnt_t; i += 256) {
    int d = dst[base + i];
    int s = src[base + i];
    int b = d >> BSHIFT;
    int r = atomicAdd(&cur[b], 1);
    stage[r] = ((d & (BNODES - 1)) << 17) | s;
    stg_b[r] = (unsigned short)b;
  }
  __syncthreads();
  for (int i = tid; i < cnt_t; i += 256) {
    int b = stg_b[i];
    int excl = scn[b] - hist[b];
    int pos = gbase[b] + (i - excl);
    if (pos < BCAP) bpacked[(size_t)b * BCAP + pos] = stage[i];
  }
}

// ---------------- degree -> dis, per bucket ----------------
__global__ __launch_bounds__(256) void degdis_kernel(
    const int* __restrict__ bpacked, const int* __restrict__ bcur,
    float* __restrict__ dis, int N) {
  __shared__ int hist[BNODES];
  int b = blockIdx.x;
  int tid = threadIdx.x;
  hist[tid] = 0;
  __syncthreads();
  int ecnt = bcur[b]; if (ecnt > BCAP) ecnt = BCAP;
  const int* bp = bpacked + (size_t)b * BCAP;
  for (int i = tid; i < ecnt; i += 256) atomicAdd(&hist[bp[i] >> 17], 1);
  __syncthreads();
  int node = (b << BSHIFT) + tid;
  if (node < N) dis[node] = rsqrtf((float)hist[tid] + 1.0f);
}

// ---------------- t1s = dis * (x @ W1) ----------------
__global__ __launch_bounds__(256) void gemm1_kernel(
    const float* __restrict__ x, const float* __restrict__ W1,
    const float* __restrict__ dis, float* __restrict__ t1s, int N) {
  __shared__ __align__(16) float xs[64 * 132];
  __shared__ __align__(16) float w1s[128 * 16];
  int tid = threadIdx.x;
  int nb = blockIdx.x * 64;
  for (int i = tid; i < 128 * 16; i += 256) w1s[i] = W1[i];
  int maxRows = N - nb; if (maxRows > 64) maxRows = 64;
  const float4* xg = (const float4*)(x + (size_t)nb * IN_CH);
  for (int i = tid; i < maxRows * 32; i += 256) {
    float4 v = xg[i];
    int row = i >> 5;
    int k4 = (i & 31) << 2;
    *((float4*)&xs[row * 132 + k4]) = v;
  }
  __syncthreads();
  int nl = tid >> 2;
  int cg = tid & 3;
  int node = nb + nl;
  float4 acc = make_float4(0.f, 0.f, 0.f, 0.f);
  const float* xrow = &xs[nl * 132];
  const float4* w4 = (const float4*)w1s;
  for (int k = 0; k < 128; ++k) {
    float xv = xrow[k];
    float4 wv = w4[k * 4 + cg];
    acc.x += xv * wv.x; acc.y += xv * wv.y;
    acc.z += xv * wv.z; acc.w += xv * wv.w;
  }
  if (node < N) {
    float dd = dis[node];
    acc.x *= dd; acc.y *= dd; acc.z *= dd; acc.w *= dd;
    *((float4*)&t1s[(size_t)node * HID + cg * 4]) = acc;
  }
}

// ------------- half-bucket gather: LDS sort + register accumulate -----------
// block = (bucket, half): 128 nodes. Filter on bit7 of dlow, sort into LDS,
// then 4 threads/node x float4 channels accumulate pre-scaled feats.
template <bool RELU>
__global__ __launch_bounds__(256) void bgather_kernel(
    const int* __restrict__ bpacked, const int* __restrict__ bcur,
    const float* __restrict__ dis, const float* __restrict__ feat,
    const float* __restrict__ bias, float* __restrict__ outf, int N) {
  __shared__ int sorted[HBCAP];    // 36.9 KB: srcs grouped by local node
  __shared__ int hist[128];
  __shared__ int scn[128];
  __shared__ int cur[128];
  int blk = blockIdx.x;
  int b = blk >> 1;
  int hbit = (blk & 1) << 7;
  int tid = threadIdx.x;
  const int* bp = bpacked + (size_t)b * BCAP;
  int ecnt = bcur[b]; if (ecnt > BCAP) ecnt = BCAP;

  if (tid < 128) hist[tid] = 0;
  __syncthreads();
  for (int i = tid; i < ecnt; i += 256) {
    int dl = bp[i] >> 17;
    if ((dl & 128) == hbit) atomicAdd(&hist[dl & 127], 1);
  }
  __syncthreads();
  if (tid < 128) scn[tid] = hist[tid];
  __syncthreads();
  for (int off = 1; off < 128; off <<= 1) {
    int t = 0;
    if (tid < 128 && tid >= off) t = scn[tid - off];
    __syncthreads();
    if (tid < 128) scn[tid] += t;
    __syncthreads();
  }
  if (tid < 128) cur[tid] = scn[tid] - hist[tid];
  __syncthreads();
  for (int i = tid; i < ecnt; i += 256) {
    int p = bp[i];
    int dl = p >> 17;
    if ((dl & 128) == hbit) {
      int r = atomicAdd(&cur[dl & 127], 1);
      if (r < HBCAP) sorted[r] = p & 0x1FFFF;
    }
  }
  __syncthreads();

  // 128 nodes x 4 quads = 512 tasks over 256 threads
  for (int it = 0; it < 2; ++it) {
    int task = it * 256 + tid;
    int nl = task >> 2;
    int q4 = (task & 3) << 2;
    int node = (b << BSHIFT) + hbit + nl;
    if (node >= N) continue;
    int beg = scn[nl] - hist[nl];
    int c = hist[nl];
    if (beg >= HBCAP) c = 0;
    else if (beg + c > HBCAP) c = HBCAP - beg;   // paranoia guard
    float dd = dis[node];
    float ax = 0.f, ay = 0.f, az = 0.f, aw = 0.f;
    int j = 0;
    for (; j + 4 <= c; j += 4) {
      int s0 = sorted[beg + j];
      int s1 = sorted[beg + j + 1];
      int s2 = sorted[beg + j + 2];
      int s3 = sorted[beg + j + 3];
      float4 f0 = *(const float4*)(feat + (size_t)s0 * HID + q4);
      float4 f1 = *(const float4*)(feat + (size_t)s1 * HID + q4);
      float4 f2 = *(const float4*)(feat + (size_t)s2 * HID + q4);
      float4 f3 = *(const float4*)(feat + (size_t)s3 * HID + q4);
      ax += (f0.x + f1.x) + (f2.x + f3.x);
      ay += (f0.y + f1.y) + (f2.y + f3.y);
      az += (f0.z + f1.z) + (f2.z + f3.z);
      aw += (f0.w + f1.w) + (f2.w + f3.w);
    }
    for (; j < c; ++j) {
      int s = sorted[beg + j];
      float4 f = *(const float4*)(feat + (size_t)s * HID + q4);
      ax += f.x; ay += f.y; az += f.z; aw += f.w;
    }
    float4 self = *(const float4*)(feat + (size_t)node * HID + q4);
    float4 r;
    r.x = dd * (ax + self.x);
    r.y = dd * (ay + self.y);
    r.z = dd * (az + self.z);
    r.w = dd * (aw + self.w);
    if (RELU) {
      float4 bb = *(const float4*)(bias + q4);
      r.x = fmaxf(r.x + bb.x, 0.f) * dd;
      r.y = fmaxf(r.y + bb.y, 0.f) * dd;
      r.z = fmaxf(r.z + bb.z, 0.f) * dd;
      r.w = fmaxf(r.w + bb.w, 0.f) * dd;
    }
    *((float4*)(outf + (size_t)node * HID + q4)) = r;
  }
}

// ---------------- out = v @ W2 + b2 ----------------
__global__ __launch_bounds__(256) void out_kernel(
    const float* __restrict__ v, const float* __restrict__ W2,
    const float* __restrict__ b2, float* __restrict__ out, int N) {
  __shared__ __align__(16) float vs[32 * 17];
  __shared__ __align__(16) float w2s[16 * 32];
  __shared__ __align__(16) float b2s[32];
  int tid = threadIdx.x;
  int nb = blockIdx.x * 32;
  for (int i = tid; i < 16 * 32; i += 256) w2s[i] = W2[i];
  if (tid < 32) b2s[tid] = b2[tid];
  for (int i = tid; i < 32 * 16; i += 256) {
    int nl = i >> 4;
    int c = i & 15;
    int node = nb + nl;
    float val = 0.f;
    if (node < N) val = v[(size_t)node * HID + c];
    vs[nl * 17 + c] = val;
  }
  __syncthreads();
  int nl = tid >> 3;
  int og = tid & 7;
  int node = nb + nl;
  float4 acc = make_float4(0.f, 0.f, 0.f, 0.f);
  const float4* w24 = (const float4*)w2s;
  const float* vrow = &vs[nl * 17];
  for (int c = 0; c < 16; ++c) {
    float vv = vrow[c];
    float4 wv = w24[c * 8 + og];
    acc.x += vv * wv.x; acc.y += vv * wv.y;
    acc.z += vv * wv.z; acc.w += vv * wv.w;
  }
  float4 bb = ((const float4*)b2s)[og];
  acc.x += bb.x; acc.y += bb.y; acc.z += bb.z; acc.w += bb.w;
  if (node < N) {
    *((float4*)&out[(size_t)node * OUT_CH + og * 4]) = acc;
  }
}

extern "C" void kernel_launch(void* const* d_in, const int* in_sizes, int n_in,
                              void* d_out, int out_size, void* d_ws, size_t ws_size,
                              hipStream_t stream) {
  const float* x  = (const float*)d_in[0];
  const int* ei   = (const int*)d_in[1];   // int64 in reference -> int32 here
  const float* W1 = (const float*)d_in[2];
  const float* b1 = (const float*)d_in[3];
  const float* W2 = (const float*)d_in[4];
  const float* b2 = (const float*)d_in[5];
  float* out = (float*)d_out;

  int N = in_sizes[0] / IN_CH;
  int E = in_sizes[1] / 2;
  const int* src = ei;
  const int* dst = ei + E;

  int nbuck = (N + BNODES - 1) >> BSHIFT;          // 391

  int*   bcur    = (int*)d_ws;                     // 512
  float* dis     = (float*)(bcur + 512);           // N
  float* t1s     = dis + N;                        // 16N (reused as v)
  float* h1s     = t1s + (size_t)N * HID;          // 16N
  int*   bpacked = (int*)(h1s + (size_t)N * HID);  // nbuck*BCAP (28.8 MB)
  float* v       = t1s;   // overlay: t1s dead after bgather1
  // total ~= 2KB + 0.4 + 6.4 + 6.4 + 28.8 MB ~= 42 MB

  hipMemsetAsync(bcur, 0, 512 * sizeof(int), stream);

  bucket_kernel<<<(E + TILE - 1) / TILE, 256, 0, stream>>>(
      src, dst, bcur, bpacked, E, nbuck);
  degdis_kernel<<<nbuck, 256, 0, stream>>>(bpacked, bcur, dis, N);
  gemm1_kernel<<<(N + 63) / 64, 256, 0, stream>>>(x, W1, dis, t1s, N);
  bgather_kernel<true><<<nbuck * 2, 256, 0, stream>>>(
      bpacked, bcur, dis, t1s, b1, h1s, N);
  bgather_kernel<false><<<nbuck * 2, 256, 0, stream>>>(
      bpacked, bcur, dis, h1s, nullptr, v, N);
  out_kernel<<<(N + 31) / 32, 256, 0, stream>>>(v, W2, b2, out, N);
}

// Round 8
// 394.433 us; speedup vs baseline: 3.6362x; 1.1236x over previous
//
#include <hip/hip_runtime.h>

// GCN 2-layer: N=100000, E=6400000, IN=128, HID=16, OUT=32.
// R8: bgather was MSHR-latency bound (26.8% occ, 4 loads in flight/thread,
// 2.0 TB/s effective). Quarter-bucket blocks (64 nodes, ~21KB LDS -> ~6
// resident blocks/CU, grid 1564) + 8-edge unroll (8 float4 loads in flight)
// + int4-vectorized sort-phase scans.
//   t1s = dis * (x@W1)
//   h1s = dis * relu(dd*(sum_in t1s[s] + t1s[self]) + b1)    [bgather1]
//   v   = dis * (sum_in h1s[s] + h1s[self])                  [bgather2]
//   out = v @ W2 + b2

#define IN_CH 128
#define HID 16
#define OUT_CH 32

#define TILE 8192        // edges per phase-A workgroup
#define BSHIFT 8         // bucket = dst >> 8  (256 nodes per bucket)
#define BNODES 256
#define BCAP 18432       // bucket capacity; E[16384], sigma 128 -> +16 sigma
#define NBUCK_MAX 512
#define QCAP 5120        // quarter-bucket capacity; E[4096], sigma 64 -> +16 sigma

// ---------------- Phase A: bucket scatter (unchanged, proven) ----------------
__global__ __launch_bounds__(256) void bucket_kernel(
    const int* __restrict__ src, const int* __restrict__ dst,
    int* __restrict__ bcur, int* __restrict__ bpacked, int E, int nbuck) {
  __shared__ int stage[TILE];
  __shared__ unsigned short stg_b[TILE];
  __shared__ int hist[NBUCK_MAX];
  __shared__ int scn[NBUCK_MAX];
  __shared__ int cur[NBUCK_MAX];
  __shared__ int gbase[NBUCK_MAX];

  int tid = threadIdx.x;
  int base = blockIdx.x * TILE;
  int cnt_t = E - base; if (cnt_t > TILE) cnt_t = TILE;

  hist[tid] = 0; hist[tid + 256] = 0;
  __syncthreads();
  for (int i = tid; i < cnt_t; i += 256)
    atomicAdd(&hist[dst[base + i] >> BSHIFT], 1);
  __syncthreads();
  scn[tid] = hist[tid]; scn[tid + 256] = hist[tid + 256];
  __syncthreads();
  for (int off = 1; off < 512; off <<= 1) {
    int a0 = (tid >= off) ? scn[tid - off] : 0;
    int i1 = tid + 256;
    int a1 = (i1 >= off) ? scn[i1 - off] : 0;
    __syncthreads();
    scn[tid] += a0; scn[i1] += a1;
    __syncthreads();
  }
  for (int b = tid; b < 512; b += 256) {
    int excl = scn[b] - hist[b];
    cur[b] = excl;
    int c = hist[b];
    gbase[b] = (b < nbuck && c > 0) ? atomicAdd(&bcur[b], c) : 0;
  }
  __syncthreads();
  for (int i = tid; i < cnt_t; i += 256) {
    int d = dst[base + i];
    int s = src[base + i];
    int b = d >> BSHIFT;
    int r = atomicAdd(&cur[b], 1);
    stage[r] = ((d & (BNODES - 1)) << 17) | s;
    stg_b[r] = (unsigned short)b;
  }
  __syncthreads();
  for (int i = tid; i < cnt_t; i += 256) {
    int b = stg_b[i];
    int excl = scn[b] - hist[b];
    int pos = gbase[b] + (i - excl);
    if (pos < BCAP) bpacked[(size_t)b * BCAP + pos] = stage[i];
  }
}

// ---------------- degree -> dis, per bucket ----------------
__global__ __launch_bounds__(256) void degdis_kernel(
    const int* __restrict__ bpacked, const int* __restrict__ bcur,
    float* __restrict__ dis, int N) {
  __shared__ int hist[BNODES];
  int b = blockIdx.x;
  int tid = threadIdx.x;
  hist[tid] = 0;
  __syncthreads();
  int ecnt = bcur[b]; if (ecnt > BCAP) ecnt = BCAP;
  const int* bp = bpacked + (size_t)b * BCAP;
  for (int i = tid; i < ecnt; i += 256) atomicAdd(&hist[bp[i] >> 17], 1);
  __syncthreads();
  int node = (b << BSHIFT) + tid;
  if (node < N) dis[node] = rsqrtf((float)hist[tid] + 1.0f);
}

// ---------------- t1s = dis * (x @ W1) ----------------
__global__ __launch_bounds__(256) void gemm1_kernel(
    const float* __restrict__ x, const float* __restrict__ W1,
    const float* __restrict__ dis, float* __restrict__ t1s, int N) {
  __shared__ __align__(16) float xs[64 * 132];
  __shared__ __align__(16) float w1s[128 * 16];
  int tid = threadIdx.x;
  int nb = blockIdx.x * 64;
  for (int i = tid; i < 128 * 16; i += 256) w1s[i] = W1[i];
  int maxRows = N - nb; if (maxRows > 64) maxRows = 64;
  const float4* xg = (const float4*)(x + (size_t)nb * IN_CH);
  for (int i = tid; i < maxRows * 32; i += 256) {
    float4 v = xg[i];
    int row = i >> 5;
    int k4 = (i & 31) << 2;
    *((float4*)&xs[row * 132 + k4]) = v;
  }
  __syncthreads();
  int nl = tid >> 2;
  int cg = tid & 3;
  int node = nb + nl;
  float4 acc = make_float4(0.f, 0.f, 0.f, 0.f);
  const float* xrow = &xs[nl * 132];
  const float4* w4 = (const float4*)w1s;
  for (int k = 0; k < 128; ++k) {
    float xv = xrow[k];
    float4 wv = w4[k * 4 + cg];
    acc.x += xv * wv.x; acc.y += xv * wv.y;
    acc.z += xv * wv.z; acc.w += xv * wv.w;
  }
  if (node < N) {
    float dd = dis[node];
    acc.x *= dd; acc.y *= dd; acc.z *= dd; acc.w *= dd;
    *((float4*)&t1s[(size_t)node * HID + cg * 4]) = acc;
  }
}

// ------- quarter-bucket gather: LDS sort + register accumulate (unroll 8) ----
// block = (bucket, quarter): 64 nodes. Filter bits 6-7 of dlow.
template <bool RELU>
__global__ __launch_bounds__(256) void bgather_kernel(
    const int* __restrict__ bpacked, const int* __restrict__ bcur,
    const float* __restrict__ dis, const float* __restrict__ feat,
    const float* __restrict__ bias, float* __restrict__ outf, int N) {
  __shared__ int sorted[QCAP];     // 20.5 KB: srcs grouped by local node
  __shared__ int hist[64];
  __shared__ int scn[64];
  __shared__ int cur[64];
  int blk = blockIdx.x;
  int b = blk >> 2;
  int quarter = blk & 3;
  int qbase = quarter << 6;        // dl offset of this quarter
  int tid = threadIdx.x;
  const int* bp = bpacked + (size_t)b * BCAP;
  int ecnt = bcur[b]; if (ecnt > BCAP) ecnt = BCAP;
  int ecnt4 = ecnt & ~3;

  if (tid < 64) hist[tid] = 0;
  __syncthreads();
  // hist pass (int4-vectorized)
  for (int i = tid * 4; i < ecnt4; i += 1024) {
    int4 p4 = *(const int4*)(bp + i);
    int dl0 = p4.x >> 17, dl1 = p4.y >> 17, dl2 = p4.z >> 17, dl3 = p4.w >> 17;
    if ((dl0 >> 6) == quarter) atomicAdd(&hist[dl0 & 63], 1);
    if ((dl1 >> 6) == quarter) atomicAdd(&hist[dl1 & 63], 1);
    if ((dl2 >> 6) == quarter) atomicAdd(&hist[dl2 & 63], 1);
    if ((dl3 >> 6) == quarter) atomicAdd(&hist[dl3 & 63], 1);
  }
  if (tid < (ecnt - ecnt4)) {
    int dl = bp[ecnt4 + tid] >> 17;
    if ((dl >> 6) == quarter) atomicAdd(&hist[dl & 63], 1);
  }
  __syncthreads();
  if (tid < 64) scn[tid] = hist[tid];
  __syncthreads();
  for (int off = 1; off < 64; off <<= 1) {
    int t = 0;
    if (tid < 64 && tid >= off) t = scn[tid - off];
    __syncthreads();
    if (tid < 64) scn[tid] += t;
    __syncthreads();
  }
  if (tid < 64) cur[tid] = scn[tid] - hist[tid];
  __syncthreads();
  // place pass (int4-vectorized)
  for (int i = tid * 4; i < ecnt4; i += 1024) {
    int4 p4 = *(const int4*)(bp + i);
    int dl0 = p4.x >> 17, dl1 = p4.y >> 17, dl2 = p4.z >> 17, dl3 = p4.w >> 17;
    if ((dl0 >> 6) == quarter) {
      int r = atomicAdd(&cur[dl0 & 63], 1);
      if (r < QCAP) sorted[r] = p4.x & 0x1FFFF;
    }
    if ((dl1 >> 6) == quarter) {
      int r = atomicAdd(&cur[dl1 & 63], 1);
      if (r < QCAP) sorted[r] = p4.y & 0x1FFFF;
    }
    if ((dl2 >> 6) == quarter) {
      int r = atomicAdd(&cur[dl2 & 63], 1);
      if (r < QCAP) sorted[r] = p4.z & 0x1FFFF;
    }
    if ((dl3 >> 6) == quarter) {
      int r = atomicAdd(&cur[dl3 & 63], 1);
      if (r < QCAP) sorted[r] = p4.w & 0x1FFFF;
    }
  }
  if (tid < (ecnt - ecnt4)) {
    int p = bp[ecnt4 + tid];
    int dl = p >> 17;
    if ((dl >> 6) == quarter) {
      int r = atomicAdd(&cur[dl & 63], 1);
      if (r < QCAP) sorted[r] = p & 0x1FFFF;
    }
  }
  __syncthreads();

  // 64 nodes x 4 quads = 256 tasks, exactly one per thread
  int nl = tid >> 2;
  int q4 = (tid & 3) << 2;
  int node = (b << BSHIFT) + qbase + nl;
  if (node >= N) return;
  int beg = scn[nl] - hist[nl];
  int c = hist[nl];
  if (beg >= QCAP) c = 0;
  else if (beg + c > QCAP) c = QCAP - beg;   // paranoia guard
  float dd = dis[node];
  float ax = 0.f, ay = 0.f, az = 0.f, aw = 0.f;
  int j = 0;
  for (; j + 8 <= c; j += 8) {
    int s0 = sorted[beg + j + 0];
    int s1 = sorted[beg + j + 1];
    int s2 = sorted[beg + j + 2];
    int s3 = sorted[beg + j + 3];
    int s4 = sorted[beg + j + 4];
    int s5 = sorted[beg + j + 5];
    int s6 = sorted[beg + j + 6];
    int s7 = sorted[beg + j + 7];
    float4 f0 = *(const float4*)(feat + (size_t)s0 * HID + q4);
    float4 f1 = *(const float4*)(feat + (size_t)s1 * HID + q4);
    float4 f2 = *(const float4*)(feat + (size_t)s2 * HID + q4);
    float4 f3 = *(const float4*)(feat + (size_t)s3 * HID + q4);
    float4 f4 = *(const float4*)(feat + (size_t)s4 * HID + q4);
    float4 f5 = *(const float4*)(feat + (size_t)s5 * HID + q4);
    float4 f6 = *(const float4*)(feat + (size_t)s6 * HID + q4);
    float4 f7 = *(const float4*)(feat + (size_t)s7 * HID + q4);
    ax += ((f0.x + f1.x) + (f2.x + f3.x)) + ((f4.x + f5.x) + (f6.x + f7.x));
    ay += ((f0.y + f1.y) + (f2.y + f3.y)) + ((f4.y + f5.y) + (f6.y + f7.y));
    az += ((f0.z + f1.z) + (f2.z + f3.z)) + ((f4.z + f5.z) + (f6.z + f7.z));
    aw += ((f0.w + f1.w) + (f2.w + f3.w)) + ((f4.w + f5.w) + (f6.w + f7.w));
  }
  for (; j < c; ++j) {
    int s = sorted[beg + j];
    float4 f = *(const float4*)(feat + (size_t)s * HID + q4);
    ax += f.x; ay += f.y; az += f.z; aw += f.w;
  }
  float4 self = *(const float4*)(feat + (size_t)node * HID + q4);
  float4 r;
  r.x = dd * (ax + self.x);
  r.y = dd * (ay + self.y);
  r.z = dd * (az + self.z);
  r.w = dd * (aw + self.w);
  if (RELU) {
    float4 bb = *(const float4*)(bias + q4);
    r.x = fmaxf(r.x + bb.x, 0.f) * dd;
    r.y = fmaxf(r.y + bb.y, 0.f) * dd;
    r.z = fmaxf(r.z + bb.z, 0.f) * dd;
    r.w = fmaxf(r.w + bb.w, 0.f) * dd;
  }
  *((float4*)(outf + (size_t)node * HID + q4)) = r;
}

// ---------------- out = v @ W2 + b2 ----------------
__global__ __launch_bounds__(256) void out_kernel(
    const float* __restrict__ v, const float* __restrict__ W2,
    const float* __restrict__ b2, float* __restrict__ out, int N) {
  __shared__ __align__(16) float vs[32 * 17];
  __shared__ __align__(16) float w2s[16 * 32];
  __shared__ __align__(16) float b2s[32];
  int tid = threadIdx.x;
  int nb = blockIdx.x * 32;
  for (int i = tid; i < 16 * 32; i += 256) w2s[i] = W2[i];
  if (tid < 32) b2s[tid] = b2[tid];
  for (int i = tid; i < 32 * 16; i += 256) {
    int nl = i >> 4;
    int c = i & 15;
    int node = nb + nl;
    float val = 0.f;
    if (node < N) val = v[(size_t)node * HID + c];
    vs[nl * 17 + c] = val;
  }
  __syncthreads();
  int nl = tid >> 3;
  int og = tid & 7;
  int node = nb + nl;
  float4 acc = make_float4(0.f, 0.f, 0.f, 0.f);
  const float4* w24 = (const float4*)w2s;
  const float* vrow = &vs[nl * 17];
  for (int c = 0; c < 16; ++c) {
    float vv = vrow[c];
    float4 wv = w24[c * 8 + og];
    acc.x += vv * wv.x; acc.y += vv * wv.y;
    acc.z += vv * wv.z; acc.w += vv * wv.w;
  }
  float4 bb = ((const float4*)b2s)[og];
  acc.x += bb.x; acc.y += bb.y; acc.z += bb.z; acc.w += bb.w;
  if (node < N) {
    *((float4*)&out[(size_t)node * OUT_CH + og * 4]) = acc;
  }
}

extern "C" void kernel_launch(void* const* d_in, const int* in_sizes, int n_in,
                              void* d_out, int out_size, void* d_ws, size_t ws_size,
                              hipStream_t stream) {
  const float* x  = (const float*)d_in[0];
  const int* ei   = (const int*)d_in[1];   // int64 in reference -> int32 here
  const float* W1 = (const float*)d_in[2];
  const float* b1 = (const float*)d_in[3];
  const float* W2 = (const float*)d_in[4];
  const float* b2 = (const float*)d_in[5];
  float* out = (float*)d_out;

  int N = in_sizes[0] / IN_CH;
  int E = in_sizes[1] / 2;
  const int* src = ei;
  const int* dst = ei + E;

  int nbuck = (N + BNODES - 1) >> BSHIFT;          // 391

  int*   bcur    = (int*)d_ws;                     // 512
  float* dis     = (float*)(bcur + 512);           // N
  float* t1s     = dis + N;                        // 16N (reused as v)
  float* h1s     = t1s + (size_t)N * HID;          // 16N
  int*   bpacked = (int*)(h1s + (size_t)N * HID);  // nbuck*BCAP (28.8 MB)
  float* v       = t1s;   // overlay: t1s dead after bgather1
  // total ~= 2KB + 0.4 + 6.4 + 6.4 + 28.8 MB ~= 42 MB

  hipMemsetAsync(bcur, 0, 512 * sizeof(int), stream);

  bucket_kernel<<<(E + TILE - 1) / TILE, 256, 0, stream>>>(
      src, dst, bcur, bpacked, E, nbuck);
  degdis_kernel<<<nbuck, 256, 0, stream>>>(bpacked, bcur, dis, N);
  gemm1_kernel<<<(N + 63) / 64, 256, 0, stream>>>(x, W1, dis, t1s, N);
  bgather_kernel<true><<<nbuck * 4, 256, 0, stream>>>(
      bpacked, bcur, dis, t1s, b1, h1s, N);
  bgather_kernel<false><<<nbuck * 4, 256, 0, stream>>>(
      bpacked, bcur, dis, h1s, nullptr, v, N);
  out_kernel<<<(N + 31) / 32, 256, 0, stream>>>(v, W2, b2, out, N);
}

// Round 9
// 372.513 us; speedup vs baseline: 3.8502x; 1.0588x over previous
//
#include <hip/hip_runtime.h>

// GCN 2-layer: N=100000, E=6400000, IN=128, HID=16, OUT=32.
// R9: sort exactly once, gather scan-free.
//   bucket_kernel: tile->bucket LDS sort, edges held in REGISTERS (one global
//     read pass), uchar stg_b + bit25 -> 48KB LDS, 3 blk/CU.
//   nodesort_kernel: per bucket, 256-bin hist+scan, rank-place srcs into
//     node-sorted CSR (4B stores confined to 68KB L2-resident window),
//     emits row_ptr/cnt/dis (degdis deleted).
//   ggather: 1 thread per (node,quad), NO LDS, contiguous CSR row, 8-unrolled
//     float4 feat loads; 4 lanes of a node = one coalesced 64B feat line.
//   t1s = dis*(x@W1); h1s = dis*relu(dd*(sum+self)+b1); v = dis*(sum+self);
//   out = v@W2 + b2.

#define IN_CH 128
#define HID 16
#define OUT_CH 32

#define TILE 8192        // edges per bucket_kernel workgroup (div 4)
#define BSHIFT 8
#define BNODES 256
#define BCAP 17408       // bucket slots; E[16384], sigma 128 -> +8 sigma, div4
#define NBUCK_MAX 512

// ---------------- Phase A: tile -> bucket scatter ----------------
__global__ __launch_bounds__(256) void bucket_kernel(
    const int* __restrict__ src, const int* __restrict__ dst,
    int* __restrict__ bcur, int* __restrict__ bpacked, int E, int nbuck) {
  __shared__ int stage[TILE];                 // 32 KB
  __shared__ unsigned char stg_b[TILE];       // 8 KB
  __shared__ int hist[NBUCK_MAX];             // 2 KB each
  __shared__ int scn[NBUCK_MAX];
  __shared__ int cur[NBUCK_MAX];
  __shared__ int gbase[NBUCK_MAX];

  int tid = threadIdx.x;
  int base = blockIdx.x * TILE;
  int cnt_t = E - base; if (cnt_t > TILE) cnt_t = TILE;
  bool full = (cnt_t == TILE);

  hist[tid] = 0; hist[tid + 256] = 0;
  __syncthreads();

  int4 d4[8], s4[8];
  if (full) {
    const int4* dv = (const int4*)(dst + base);
    #pragma unroll
    for (int k = 0; k < 8; ++k) d4[k] = dv[tid + 256 * k];
    #pragma unroll
    for (int k = 0; k < 8; ++k) {
      atomicAdd(&hist[d4[k].x >> BSHIFT], 1);
      atomicAdd(&hist[d4[k].y >> BSHIFT], 1);
      atomicAdd(&hist[d4[k].z >> BSHIFT], 1);
      atomicAdd(&hist[d4[k].w >> BSHIFT], 1);
    }
    const int4* sv = (const int4*)(src + base);
    #pragma unroll
    for (int k = 0; k < 8; ++k) s4[k] = sv[tid + 256 * k];  // overlap w/ scan
  } else {
    for (int i = tid; i < cnt_t; i += 256)
      atomicAdd(&hist[dst[base + i] >> BSHIFT], 1);
  }
  __syncthreads();
  scn[tid] = hist[tid]; scn[tid + 256] = hist[tid + 256];
  __syncthreads();
  for (int off = 1; off < 512; off <<= 1) {
    int a0 = (tid >= off) ? scn[tid - off] : 0;
    int i1 = tid + 256;
    int a1 = (i1 >= off) ? scn[i1 - off] : 0;
    __syncthreads();
    scn[tid] += a0; scn[i1] += a1;
    __syncthreads();
  }
  for (int b = tid; b < 512; b += 256) {
    int excl = scn[b] - hist[b];
    cur[b] = excl;
    int c = hist[b];
    gbase[b] = (b < nbuck && c > 0) ? atomicAdd(&bcur[b], c) : 0;
  }
  __syncthreads();
  if (full) {
    #pragma unroll
    for (int k = 0; k < 8; ++k) {
      int dd[4] = {d4[k].x, d4[k].y, d4[k].z, d4[k].w};
      int ss[4] = {s4[k].x, s4[k].y, s4[k].z, s4[k].w};
      #pragma unroll
      for (int c = 0; c < 4; ++c) {
        int d = dd[c], s = ss[c];
        int b = d >> BSHIFT;
        int r = atomicAdd(&cur[b], 1);
        stage[r] = ((b >> 8) << 25) | ((d & 255) << 17) | s;
        stg_b[r] = (unsigned char)b;
      }
    }
  } else {
    for (int i = tid; i < cnt_t; i += 256) {
      int d = dst[base + i];
      int s = src[base + i];
      int b = d >> BSHIFT;
      int r = atomicAdd(&cur[b], 1);
      stage[r] = ((b >> 8) << 25) | ((d & 255) << 17) | s;
      stg_b[r] = (unsigned char)b;
    }
  }
  __syncthreads();
  for (int i = tid; i < cnt_t; i += 256) {
    int sv = stage[i];
    int b = stg_b[i] | (((sv >> 25) & 1) << 8);
    int excl = scn[b] - hist[b];
    int pos = gbase[b] + (i - excl);
    if (pos < BCAP) bpacked[(size_t)b * BCAP + pos] = sv & 0x1FFFFFF;
  }
}

// -------- nodesort: bucket -> node-sorted CSR + row_ptr/cnt/dis --------
__global__ __launch_bounds__(256) void nodesort_kernel(
    const int* __restrict__ bpacked, const int* __restrict__ bcur,
    int* __restrict__ csr, int* __restrict__ row_ptr, int* __restrict__ cnt,
    float* __restrict__ dis, int N) {
  __shared__ int h[BNODES];
  __shared__ int sc[BNODES];
  __shared__ int cu[BNODES];
  int b = blockIdx.x;
  int tid = threadIdx.x;
  h[tid] = 0;
  __syncthreads();
  int ecnt = bcur[b]; if (ecnt > BCAP) ecnt = BCAP;
  int ecnt4 = ecnt & ~3;
  const int* bp = bpacked + (size_t)b * BCAP;
  for (int i4 = tid; i4 * 4 < ecnt4; i4 += 256) {
    int4 p = ((const int4*)bp)[i4];
    atomicAdd(&h[(p.x >> 17) & 255], 1);
    atomicAdd(&h[(p.y >> 17) & 255], 1);
    atomicAdd(&h[(p.z >> 17) & 255], 1);
    atomicAdd(&h[(p.w >> 17) & 255], 1);
  }
  if (ecnt4 + tid < ecnt) atomicAdd(&h[(bp[ecnt4 + tid] >> 17) & 255], 1);
  __syncthreads();
  sc[tid] = h[tid];
  __syncthreads();
  for (int off = 1; off < 256; off <<= 1) {
    int t = (tid >= off) ? sc[tid - off] : 0;
    __syncthreads();
    sc[tid] += t;
    __syncthreads();
  }
  cu[tid] = sc[tid] - h[tid];
  __syncthreads();
  int* cb = csr + (size_t)b * BCAP;
  for (int i4 = tid; i4 * 4 < ecnt4; i4 += 256) {
    int4 p = ((const int4*)bp)[i4];
    int r;
    r = atomicAdd(&cu[(p.x >> 17) & 255], 1); cb[r] = p.x & 0x1FFFF;
    r = atomicAdd(&cu[(p.y >> 17) & 255], 1); cb[r] = p.y & 0x1FFFF;
    r = atomicAdd(&cu[(p.z >> 17) & 255], 1); cb[r] = p.z & 0x1FFFF;
    r = atomicAdd(&cu[(p.w >> 17) & 255], 1); cb[r] = p.w & 0x1FFFF;
  }
  if (ecnt4 + tid < ecnt) {
    int p = bp[ecnt4 + tid];
    int r = atomicAdd(&cu[(p >> 17) & 255], 1);
    cb[r] = p & 0x1FFFF;
  }
  int node = (b << BSHIFT) + tid;
  if (node < N) {
    row_ptr[node] = b * BCAP + (sc[tid] - h[tid]);
    cnt[node] = h[tid];
    dis[node] = rsqrtf((float)h[tid] + 1.0f);
  }
}

// ---------------- t1s = dis * (x @ W1) ----------------
__global__ __launch_bounds__(256) void gemm1_kernel(
    const float* __restrict__ x, const float* __restrict__ W1,
    const float* __restrict__ dis, float* __restrict__ t1s, int N) {
  __shared__ __align__(16) float xs[64 * 132];
  __shared__ __align__(16) float w1s[128 * 16];
  int tid = threadIdx.x;
  int nb = blockIdx.x * 64;
  for (int i = tid; i < 128 * 16; i += 256) w1s[i] = W1[i];
  int maxRows = N - nb; if (maxRows > 64) maxRows = 64;
  const float4* xg = (const float4*)(x + (size_t)nb * IN_CH);
  for (int i = tid; i < maxRows * 32; i += 256) {
    float4 v = xg[i];
    int row = i >> 5;
    int k4 = (i & 31) << 2;
    *((float4*)&xs[row * 132 + k4]) = v;
  }
  __syncthreads();
  int nl = tid >> 2;
  int cg = tid & 3;
  int node = nb + nl;
  float4 acc = make_float4(0.f, 0.f, 0.f, 0.f);
  const float* xrow = &xs[nl * 132];
  const float4* w4 = (const float4*)w1s;
  for (int k = 0; k < 128; ++k) {
    float xv = xrow[k];
    float4 wv = w4[k * 4 + cg];
    acc.x += xv * wv.x; acc.y += xv * wv.y;
    acc.z += xv * wv.z; acc.w += xv * wv.w;
  }
  if (node < N) {
    float dd = dis[node];
    acc.x *= dd; acc.y *= dd; acc.z *= dd; acc.w *= dd;
    *((float4*)&t1s[(size_t)node * HID + cg * 4]) = acc;
  }
}

// ---------- flat gather: 1 thread per (node, quad), no LDS ----------
template <bool RELU>
__global__ __launch_bounds__(256) void ggather_kernel(
    const int* __restrict__ row_ptr, const int* __restrict__ cnt,
    const int* __restrict__ csr, const float* __restrict__ dis,
    const float* __restrict__ feat, const float* __restrict__ bias,
    float* __restrict__ outf, int N) {
  int gid = blockIdx.x * 256 + threadIdx.x;
  int node = gid >> 2;
  if (node >= N) return;
  int q4 = (gid & 3) << 2;
  int beg = row_ptr[node];
  int c = cnt[node];
  float dd = dis[node];
  const int* row = csr + beg;
  float ax = 0.f, ay = 0.f, az = 0.f, aw = 0.f;
  int j = 0;
  for (; j + 8 <= c; j += 8) {
    int s0 = row[j + 0];
    int s1 = row[j + 1];
    int s2 = row[j + 2];
    int s3 = row[j + 3];
    int s4 = row[j + 4];
    int s5 = row[j + 5];
    int s6 = row[j + 6];
    int s7 = row[j + 7];
    float4 f0 = *(const float4*)(feat + (size_t)s0 * HID + q4);
    float4 f1 = *(const float4*)(feat + (size_t)s1 * HID + q4);
    float4 f2 = *(const float4*)(feat + (size_t)s2 * HID + q4);
    float4 f3 = *(const float4*)(feat + (size_t)s3 * HID + q4);
    float4 f4 = *(const float4*)(feat + (size_t)s4 * HID + q4);
    float4 f5 = *(const float4*)(feat + (size_t)s5 * HID + q4);
    float4 f6 = *(const float4*)(feat + (size_t)s6 * HID + q4);
    float4 f7 = *(const float4*)(feat + (size_t)s7 * HID + q4);
    ax += ((f0.x + f1.x) + (f2.x + f3.x)) + ((f4.x + f5.x) + (f6.x + f7.x));
    ay += ((f0.y + f1.y) + (f2.y + f3.y)) + ((f4.y + f5.y) + (f6.y + f7.y));
    az += ((f0.z + f1.z) + (f2.z + f3.z)) + ((f4.z + f5.z) + (f6.z + f7.z));
    aw += ((f0.w + f1.w) + (f2.w + f3.w)) + ((f4.w + f5.w) + (f6.w + f7.w));
  }
  for (; j < c; ++j) {
    int s = row[j];
    float4 f = *(const float4*)(feat + (size_t)s * HID + q4);
    ax += f.x; ay += f.y; az += f.z; aw += f.w;
  }
  float4 self = *(const float4*)(feat + (size_t)node * HID + q4);
  float4 r;
  r.x = dd * (ax + self.x);
  r.y = dd * (ay + self.y);
  r.z = dd * (az + self.z);
  r.w = dd * (aw + self.w);
  if (RELU) {
    float4 bb = *(const float4*)(bias + q4);
    r.x = fmaxf(r.x + bb.x, 0.f) * dd;
    r.y = fmaxf(r.y + bb.y, 0.f) * dd;
    r.z = fmaxf(r.z + bb.z, 0.f) * dd;
    r.w = fmaxf(r.w + bb.w, 0.f) * dd;
  }
  *((float4*)(outf + (size_t)node * HID + q4)) = r;
}

// ---------------- out = v @ W2 + b2 ----------------
__global__ __launch_bounds__(256) void out_kernel(
    const float* __restrict__ v, const float* __restrict__ W2,
    const float* __restrict__ b2, float* __restrict__ out, int N) {
  __shared__ __align__(16) float vs[32 * 17];
  __shared__ __align__(16) float w2s[16 * 32];
  __shared__ __align__(16) float b2s[32];
  int tid = threadIdx.x;
  int nb = blockIdx.x * 32;
  for (int i = tid; i < 16 * 32; i += 256) w2s[i] = W2[i];
  if (tid < 32) b2s[tid] = b2[tid];
  for (int i = tid; i < 32 * 16; i += 256) {
    int nl = i >> 4;
    int c = i & 15;
    int node = nb + nl;
    float val = 0.f;
    if (node < N) val = v[(size_t)node * HID + c];
    vs[nl * 17 + c] = val;
  }
  __syncthreads();
  int nl = tid >> 3;
  int og = tid & 7;
  int node = nb + nl;
  float4 acc = make_float4(0.f, 0.f, 0.f, 0.f);
  const float4* w24 = (const float4*)w2s;
  const float* vrow = &vs[nl * 17];
  for (int c = 0; c < 16; ++c) {
    float vv = vrow[c];
    float4 wv = w24[c * 8 + og];
    acc.x += vv * wv.x; acc.y += vv * wv.y;
    acc.z += vv * wv.z; acc.w += vv * wv.w;
  }
  float4 bb = ((const float4*)b2s)[og];
  acc.x += bb.x; acc.y += bb.y; acc.z += bb.z; acc.w += bb.w;
  if (node < N) {
    *((float4*)&out[(size_t)node * OUT_CH + og * 4]) = acc;
  }
}

extern "C" void kernel_launch(void* const* d_in, const int* in_sizes, int n_in,
                              void* d_out, int out_size, void* d_ws, size_t ws_size,
                              hipStream_t stream) {
  const float* x  = (const float*)d_in[0];
  const int* ei   = (const int*)d_in[1];   // int64 in reference -> int32 here
  const float* W1 = (const float*)d_in[2];
  const float* b1 = (const float*)d_in[3];
  const float* W2 = (const float*)d_in[4];
  const float* b2 = (const float*)d_in[5];
  float* out = (float*)d_out;

  int N = in_sizes[0] / IN_CH;
  int E = in_sizes[1] / 2;
  const int* src = ei;
  const int* dst = ei + E;

  int nbuck = (N + BNODES - 1) >> BSHIFT;          // 391

  int*   bcur    = (int*)d_ws;                     // 512
  float* dis     = (float*)(bcur + 512);           // N
  float* t1s     = dis + N;                        // 16N (reused as v)
  float* h1s     = t1s + (size_t)N * HID;          // 16N
  int*   row_ptr = (int*)(h1s + (size_t)N * HID);  // N
  int*   cnt     = row_ptr + N;                    // N
  int*   bpacked = cnt + N;                        // nbuck*BCAP (27.2 MB)
  int*   csr     = bpacked + (size_t)nbuck * BCAP; // nbuck*BCAP (27.2 MB)
  float* v       = t1s;   // overlay: t1s dead after ggather1
  // total ~= 2KB + 14.0 MB + 2*27.2 MB ~= 68.5 MB

  hipMemsetAsync(bcur, 0, 512 * sizeof(int), stream);

  bucket_kernel<<<(E + TILE - 1) / TILE, 256, 0, stream>>>(
      src, dst, bcur, bpacked, E, nbuck);
  nodesort_kernel<<<nbuck, 256, 0, stream>>>(
      bpacked, bcur, csr, row_ptr, cnt, dis, N);
  gemm1_kernel<<<(N + 63) / 64, 256, 0, stream>>>(x, W1, dis, t1s, N);
  ggather_kernel<true><<<((size_t)N * 4 + 255) / 256, 256, 0, stream>>>(
      row_ptr, cnt, csr, dis, t1s, b1, h1s, N);
  ggather_kernel<false><<<((size_t)N * 4 + 255) / 256, 256, 0, stream>>>(
      row_ptr, cnt, csr, dis, h1s, nullptr, v, N);
  out_kernel<<<(N + 31) / 32, 256, 0, stream>>>(v, W2, b2, out, N);
}

// Round 10
// 297.844 us; speedup vs baseline: 4.8154x; 1.2507x over previous
//
#include <hip/hip_runtime.h>

// GCN 2-layer: N=100000, E=6400000, IN=128, HID=16, OUT=32.
// R10: (1) fp16 feature storage (fp32 accumulate): 3.2MB table fits per-XCD
// L2 -> kills ggather's 240MB HBM refetch; (2) 8 threads/node gather
// (edge-parity halves + shfl combine) -> 2x waves, occ 51->~75%;
// (3) bucket_kernel 512 thr, nodesort 1024 thr (sorts were 1.5-3 blk/CU).
//   t1h = fp16(dis*(x@W1)); h1h = fp16(dis*relu(dd*(sum+self)+b1));
//   v = dis*(sum+self) fp32; out = v@W2 + b2.

#define IN_CH 128
#define HID 16
#define OUT_CH 32

#define TILE 8192        // edges per bucket_kernel workgroup (div 4)
#define BSHIFT 8
#define BNODES 256
#define BCAP 17408       // bucket slots; E[16384], sigma 128 -> +8 sigma, div4
#define NBUCK_MAX 512

typedef __attribute__((ext_vector_type(4))) _Float16 half4;

// ---------------- Phase A: tile -> bucket scatter (512 threads) -------------
__global__ __launch_bounds__(512) void bucket_kernel(
    const int* __restrict__ src, const int* __restrict__ dst,
    int* __restrict__ bcur, int* __restrict__ bpacked, int E, int nbuck) {
  __shared__ int stage[TILE];                 // 32 KB
  __shared__ unsigned char stg_b[TILE];       // 8 KB
  __shared__ int hist[NBUCK_MAX];             // 2 KB each
  __shared__ int scn[NBUCK_MAX];
  __shared__ int cur[NBUCK_MAX];
  __shared__ int gbase[NBUCK_MAX];

  int tid = threadIdx.x;
  int base = blockIdx.x * TILE;
  int cnt_t = E - base; if (cnt_t > TILE) cnt_t = TILE;
  bool full = (cnt_t == TILE);

  hist[tid] = 0;
  __syncthreads();

  int4 d4[4], s4[4];
  if (full) {
    const int4* dv = (const int4*)(dst + base);
    #pragma unroll
    for (int k = 0; k < 4; ++k) d4[k] = dv[tid + 512 * k];
    #pragma unroll
    for (int k = 0; k < 4; ++k) {
      atomicAdd(&hist[d4[k].x >> BSHIFT], 1);
      atomicAdd(&hist[d4[k].y >> BSHIFT], 1);
      atomicAdd(&hist[d4[k].z >> BSHIFT], 1);
      atomicAdd(&hist[d4[k].w >> BSHIFT], 1);
    }
    const int4* sv = (const int4*)(src + base);
    #pragma unroll
    for (int k = 0; k < 4; ++k) s4[k] = sv[tid + 512 * k];  // overlap w/ scan
  } else {
    for (int i = tid; i < cnt_t; i += 512)
      atomicAdd(&hist[dst[base + i] >> BSHIFT], 1);
  }
  __syncthreads();
  scn[tid] = hist[tid];
  __syncthreads();
  for (int off = 1; off < 512; off <<= 1) {
    int a0 = (tid >= off) ? scn[tid - off] : 0;
    __syncthreads();
    scn[tid] += a0;
    __syncthreads();
  }
  {
    int b = tid;
    int excl = scn[b] - hist[b];
    cur[b] = excl;
    int c = hist[b];
    gbase[b] = (b < nbuck && c > 0) ? atomicAdd(&bcur[b], c) : 0;
  }
  __syncthreads();
  if (full) {
    #pragma unroll
    for (int k = 0; k < 4; ++k) {
      int dd[4] = {d4[k].x, d4[k].y, d4[k].z, d4[k].w};
      int ss[4] = {s4[k].x, s4[k].y, s4[k].z, s4[k].w};
      #pragma unroll
      for (int c = 0; c < 4; ++c) {
        int d = dd[c], s = ss[c];
        int b = d >> BSHIFT;
        int r = atomicAdd(&cur[b], 1);
        stage[r] = ((b >> 8) << 25) | ((d & 255) << 17) | s;
        stg_b[r] = (unsigned char)b;
      }
    }
  } else {
    for (int i = tid; i < cnt_t; i += 512) {
      int d = dst[base + i];
      int s = src[base + i];
      int b = d >> BSHIFT;
      int r = atomicAdd(&cur[b], 1);
      stage[r] = ((b >> 8) << 25) | ((d & 255) << 17) | s;
      stg_b[r] = (unsigned char)b;
    }
  }
  __syncthreads();
  for (int i = tid; i < cnt_t; i += 512) {
    int sv = stage[i];
    int b = stg_b[i] | (((sv >> 25) & 1) << 8);
    int excl = scn[b] - hist[b];
    int pos = gbase[b] + (i - excl);
    if (pos < BCAP) bpacked[(size_t)b * BCAP + pos] = sv & 0x1FFFFFF;
  }
}

// -------- nodesort (1024 thr): bucket -> node-sorted CSR + row_ptr/cnt/dis --
__global__ __launch_bounds__(1024) void nodesort_kernel(
    const int* __restrict__ bpacked, const int* __restrict__ bcur,
    int* __restrict__ csr, int* __restrict__ row_ptr, int* __restrict__ cnt,
    float* __restrict__ dis, int N) {
  __shared__ int h[BNODES];
  __shared__ int sc[BNODES];
  __shared__ int cu[BNODES];
  int b = blockIdx.x;
  int tid = threadIdx.x;
  if (tid < BNODES) h[tid] = 0;
  __syncthreads();
  int ecnt = bcur[b]; if (ecnt > BCAP) ecnt = BCAP;
  int ecnt4 = ecnt & ~3;
  const int* bp = bpacked + (size_t)b * BCAP;
  for (int i4 = tid; i4 * 4 < ecnt4; i4 += 1024) {
    int4 p = ((const int4*)bp)[i4];
    atomicAdd(&h[(p.x >> 17) & 255], 1);
    atomicAdd(&h[(p.y >> 17) & 255], 1);
    atomicAdd(&h[(p.z >> 17) & 255], 1);
    atomicAdd(&h[(p.w >> 17) & 255], 1);
  }
  if (ecnt4 + tid < ecnt) atomicAdd(&h[(bp[ecnt4 + tid] >> 17) & 255], 1);
  __syncthreads();
  if (tid < BNODES) sc[tid] = h[tid];
  __syncthreads();
  for (int off = 1; off < BNODES; off <<= 1) {
    int t = 0;
    if (tid < BNODES && tid >= off) t = sc[tid - off];
    __syncthreads();
    if (tid < BNODES) sc[tid] += t;
    __syncthreads();
  }
  if (tid < BNODES) cu[tid] = sc[tid] - h[tid];
  __syncthreads();
  int* cb = csr + (size_t)b * BCAP;
  for (int i4 = tid; i4 * 4 < ecnt4; i4 += 1024) {
    int4 p = ((const int4*)bp)[i4];
    int r;
    r = atomicAdd(&cu[(p.x >> 17) & 255], 1); cb[r] = p.x & 0x1FFFF;
    r = atomicAdd(&cu[(p.y >> 17) & 255], 1); cb[r] = p.y & 0x1FFFF;
    r = atomicAdd(&cu[(p.z >> 17) & 255], 1); cb[r] = p.z & 0x1FFFF;
    r = atomicAdd(&cu[(p.w >> 17) & 255], 1); cb[r] = p.w & 0x1FFFF;
  }
  if (ecnt4 + tid < ecnt) {
    int p = bp[ecnt4 + tid];
    int r = atomicAdd(&cu[(p >> 17) & 255], 1);
    cb[r] = p & 0x1FFFF;
  }
  if (tid < BNODES) {
    int node = (b << BSHIFT) + tid;
    if (node < N) {
      row_ptr[node] = b * BCAP + (sc[tid] - h[tid]);
      cnt[node] = h[tid];
      dis[node] = rsqrtf((float)h[tid] + 1.0f);
    }
  }
}

// ---------------- t1h = fp16(dis * (x @ W1)) ----------------
__global__ __launch_bounds__(256) void gemm1_kernel(
    const float* __restrict__ x, const float* __restrict__ W1,
    const float* __restrict__ dis, _Float16* __restrict__ t1h, int N) {
  __shared__ __align__(16) float xs[64 * 132];
  __shared__ __align__(16) float w1s[128 * 16];
  int tid = threadIdx.x;
  int nb = blockIdx.x * 64;
  for (int i = tid; i < 128 * 16; i += 256) w1s[i] = W1[i];
  int maxRows = N - nb; if (maxRows > 64) maxRows = 64;
  const float4* xg = (const float4*)(x + (size_t)nb * IN_CH);
  for (int i = tid; i < maxRows * 32; i += 256) {
    float4 v = xg[i];
    int row = i >> 5;
    int k4 = (i & 31) << 2;
    *((float4*)&xs[row * 132 + k4]) = v;
  }
  __syncthreads();
  int nl = tid >> 2;
  int cg = tid & 3;
  int node = nb + nl;
  float4 acc = make_float4(0.f, 0.f, 0.f, 0.f);
  const float* xrow = &xs[nl * 132];
  const float4* w4 = (const float4*)w1s;
  for (int k = 0; k < 128; ++k) {
    float xv = xrow[k];
    float4 wv = w4[k * 4 + cg];
    acc.x += xv * wv.x; acc.y += xv * wv.y;
    acc.z += xv * wv.z; acc.w += xv * wv.w;
  }
  if (node < N) {
    float dd = dis[node];
    half4 hv;
    hv.x = (_Float16)(acc.x * dd);
    hv.y = (_Float16)(acc.y * dd);
    hv.z = (_Float16)(acc.z * dd);
    hv.w = (_Float16)(acc.w * dd);
    *((half4*)&t1h[(size_t)node * HID + cg * 4]) = hv;
  }
}

// ------ flat gather: 8 threads/node (edge-parity halves), fp16 feats -------
// RELU=true: layer1, writes fp16 h1h. RELU=false: layer2, writes fp32 v.
template <bool RELU>
__global__ __launch_bounds__(256) void ggather_kernel(
    const int* __restrict__ row_ptr, const int* __restrict__ cnt,
    const int* __restrict__ csr, const float* __restrict__ dis,
    const _Float16* __restrict__ feat, const float* __restrict__ bias,
    _Float16* __restrict__ out16, float* __restrict__ out32, int N) {
  int gid = blockIdx.x * 256 + threadIdx.x;
  int node = gid >> 3;
  if (node >= N) return;
  int half = (gid >> 2) & 1;
  int q4 = (gid & 3) << 2;
  int beg = row_ptr[node];
  int c = cnt[node];
  const int* row = csr + beg;
  float ax = 0.f, ay = 0.f, az = 0.f, aw = 0.f;
  int j = half;
  for (; j + 14 < c; j += 16) {   // 8 edges per half per iter
    int s0 = row[j + 0];
    int s1 = row[j + 2];
    int s2 = row[j + 4];
    int s3 = row[j + 6];
    int s4 = row[j + 8];
    int s5 = row[j + 10];
    int s6 = row[j + 12];
    int s7 = row[j + 14];
    half4 f0 = *(const half4*)(feat + (size_t)s0 * HID + q4);
    half4 f1 = *(const half4*)(feat + (size_t)s1 * HID + q4);
    half4 f2 = *(const half4*)(feat + (size_t)s2 * HID + q4);
    half4 f3 = *(const half4*)(feat + (size_t)s3 * HID + q4);
    half4 f4 = *(const half4*)(feat + (size_t)s4 * HID + q4);
    half4 f5 = *(const half4*)(feat + (size_t)s5 * HID + q4);
    half4 f6 = *(const half4*)(feat + (size_t)s6 * HID + q4);
    half4 f7 = *(const half4*)(feat + (size_t)s7 * HID + q4);
    ax += ((float)f0.x + (float)f1.x) + ((float)f2.x + (float)f3.x)
        + ((float)f4.x + (float)f5.x) + ((float)f6.x + (float)f7.x);
    ay += ((float)f0.y + (float)f1.y) + ((float)f2.y + (float)f3.y)
        + ((float)f4.y + (float)f5.y) + ((float)f6.y + (float)f7.y);
    az += ((float)f0.z + (float)f1.z) + ((float)f2.z + (float)f3.z)
        + ((float)f4.z + (float)f5.z) + ((float)f6.z + (float)f7.z);
    aw += ((float)f0.w + (float)f1.w) + ((float)f2.w + (float)f3.w)
        + ((float)f4.w + (float)f5.w) + ((float)f6.w + (float)f7.w);
  }
  for (; j < c; j += 2) {
    int s = row[j];
    half4 f = *(const half4*)(feat + (size_t)s * HID + q4);
    ax += (float)f.x; ay += (float)f.y; az += (float)f.z; aw += (float)f.w;
  }
  // combine the two parity halves (lane and lane+4 of this node's 8 lanes)
  ax += __shfl_down(ax, 4);
  ay += __shfl_down(ay, 4);
  az += __shfl_down(az, 4);
  aw += __shfl_down(aw, 4);
  if (half == 0) {
    float dd = dis[node];
    half4 sf = *(const half4*)(feat + (size_t)node * HID + q4);
    float rx = dd * (ax + (float)sf.x);
    float ry = dd * (ay + (float)sf.y);
    float rz = dd * (az + (float)sf.z);
    float rw = dd * (aw + (float)sf.w);
    if (RELU) {
      float4 bb = *(const float4*)(bias + q4);
      rx = fmaxf(rx + bb.x, 0.f) * dd;
      ry = fmaxf(ry + bb.y, 0.f) * dd;
      rz = fmaxf(rz + bb.z, 0.f) * dd;
      rw = fmaxf(rw + bb.w, 0.f) * dd;
      half4 hv;
      hv.x = (_Float16)rx; hv.y = (_Float16)ry;
      hv.z = (_Float16)rz; hv.w = (_Float16)rw;
      *((half4*)&out16[(size_t)node * HID + q4]) = hv;
    } else {
      float4 r = make_float4(rx, ry, rz, rw);
      *((float4*)&out32[(size_t)node * HID + q4]) = r;
    }
  }
}

// ---------------- out = v @ W2 + b2 ----------------
__global__ __launch_bounds__(256) void out_kernel(
    const float* __restrict__ v, const float* __restrict__ W2,
    const float* __restrict__ b2, float* __restrict__ out, int N) {
  __shared__ __align__(16) float vs[32 * 17];
  __shared__ __align__(16) float w2s[16 * 32];
  __shared__ __align__(16) float b2s[32];
  int tid = threadIdx.x;
  int nb = blockIdx.x * 32;
  for (int i = tid; i < 16 * 32; i += 256) w2s[i] = W2[i];
  if (tid < 32) b2s[tid] = b2[tid];
  for (int i = tid; i < 32 * 16; i += 256) {
    int nl = i >> 4;
    int c = i & 15;
    int node = nb + nl;
    float val = 0.f;
    if (node < N) val = v[(size_t)node * HID + c];
    vs[nl * 17 + c] = val;
  }
  __syncthreads();
  int nl = tid >> 3;
  int og = tid & 7;
  int node = nb + nl;
  float4 acc = make_float4(0.f, 0.f, 0.f, 0.f);
  const float4* w24 = (const float4*)w2s;
  const float* vrow = &vs[nl * 17];
  for (int c = 0; c < 16; ++c) {
    float vv = vrow[c];
    float4 wv = w24[c * 8 + og];
    acc.x += vv * wv.x; acc.y += vv * wv.y;
    acc.z += vv * wv.z; acc.w += vv * wv.w;
  }
  float4 bb = ((const float4*)b2s)[og];
  acc.x += bb.x; acc.y += bb.y; acc.z += bb.z; acc.w += bb.w;
  if (node < N) {
    *((float4*)&out[(size_t)node * OUT_CH + og * 4]) = acc;
  }
}

extern "C" void kernel_launch(void* const* d_in, const int* in_sizes, int n_in,
                              void* d_out, int out_size, void* d_ws, size_t ws_size,
                              hipStream_t stream) {
  const float* x  = (const float*)d_in[0];
  const int* ei   = (const int*)d_in[1];   // int64 in reference -> int32 here
  const float* W1 = (const float*)d_in[2];
  const float* b1 = (const float*)d_in[3];
  const float* W2 = (const float*)d_in[4];
  const float* b2 = (const float*)d_in[5];
  float* out = (float*)d_out;

  int N = in_sizes[0] / IN_CH;
  int E = in_sizes[1] / 2;
  const int* src = ei;
  const int* dst = ei + E;

  int nbuck = (N + BNODES - 1) >> BSHIFT;          // 391

  int*      bcur    = (int*)d_ws;                       // 512
  float*    dis     = (float*)(bcur + 512);             // N
  float*    v       = dis + N;                          // 16N fp32
  int*      row_ptr = (int*)(v + (size_t)N * HID);      // N
  int*      cnt     = row_ptr + N;                      // N
  _Float16* t1h     = (_Float16*)(cnt + N);             // 16N fp16 (3.2MB)
  _Float16* h1h     = t1h + (size_t)N * HID;            // 16N fp16 (3.2MB)
  int*      bpacked = (int*)(h1h + (size_t)N * HID);    // nbuck*BCAP (27.2MB)
  int*      csr     = bpacked + (size_t)nbuck * BCAP;   // nbuck*BCAP (27.2MB)
  // total ~= 2KB + 7.6MB + 6.4MB + 54.4MB ~= 68.5 MB

  hipMemsetAsync(bcur, 0, 512 * sizeof(int), stream);

  bucket_kernel<<<(E + TILE - 1) / TILE, 512, 0, stream>>>(
      src, dst, bcur, bpacked, E, nbuck);
  nodesort_kernel<<<nbuck, 1024, 0, stream>>>(
      bpacked, bcur, csr, row_ptr, cnt, dis, N);
  gemm1_kernel<<<(N + 63) / 64, 256, 0, stream>>>(x, W1, dis, t1h, N);
  ggather_kernel<true><<<((size_t)N * 8 + 255) / 256, 256, 0, stream>>>(
      row_ptr, cnt, csr, dis, t1h, b1, h1h, nullptr, N);
  ggather_kernel<false><<<((size_t)N * 8 + 255) / 256, 256, 0, stream>>>(
      row_ptr, cnt, csr, dis, h1h, nullptr, nullptr, v, N);
  out_kernel<<<(N + 31) / 32, 256, 0, stream>>>(v, W2, b2, out, N);
}